// Round 16
// baseline (76.992 us; speedup 1.0000x reference)
//
#include <hip/hip_runtime.h>
#include <hip/hip_bf16.h>

// DCRNN single-step, algebraically reduced (proven rounds 2-15):
//   xm = x * mask
//   Z  = sigmoid(xm @ WzE + bz),  WzE = w_z[0,0][:256] + w_z[1,0][:256]
//   Ht = tanh   (xm @ WhE + bh)
//   h  = elu((1 - Z) * Ht)         // H=0 -> Z*H drops; R/w_r/b_r dead; edges dead
//   out = h @ w_lin.T + b_lin      // f32 output
//
// Precision: single-bf16 MFMA both sides (x-hi * W-hi), absmax 0.015625 (R12-R15).
// Round-16 (R13 base): latency-overlap round, bit-identical arithmetic —
//  (1) k-split staging: k<128 staged before barrier-1; k>=128 register-prefetched
//      in two 16-reg chunks under gate kb=0..3 (hand-counted vmcnt: gate-2 uses
//      vmcnt(6) to skip the in-flight x loads; vmcnt(63)=no-op slots), extra
//      barrier before kb=4.
//  (2) out-weights: depth-2 named-register prefetch (fully unrolled ping-pong).

typedef __attribute__((ext_vector_type(8))) short bf16x8;   // 8 bf16 = 4 VGPR
typedef __attribute__((ext_vector_type(4))) float f32x4;

constexpr int N_ROWS = 50000;
constexpr int CIN  = 256;
constexpr int COUT = 64;
constexpr int BM   = 64;

__device__ inline unsigned short f2bf(float f) {          // RNE f32 -> bf16 bits
    union { float f; unsigned u; } v; v.f = f;
    unsigned r = v.u + 0x7fffu + ((v.u >> 16) & 1u);
    return (unsigned short)(r >> 16);
}
__device__ inline f32x4 mfma16(bf16x8 a, bf16x8 b, f32x4 c) {
    return __builtin_amdgcn_mfma_f32_16x16x32_bf16(a, b, c, 0, 0, 0);
}
__device__ __forceinline__ void gload16(const void* g, void* l) {
    // one fragment: 64 lanes x 16 B -> LDS at base + lane*16 (async, vmcnt-counted)
    __builtin_amdgcn_global_load_lds(
        (const __attribute__((address_space(1))) char*)g,
        (__attribute__((address_space(3))) char*)l, 16, 0, 0);
}

// ---------------- weight prep: B-fragment-ordered bf16 (hi only; proven R7-R15) ----------------
// Fragment f holds, for lane l, 8 bf16: B[k = kb*32 + (l>>4)*8 + j][n = nf*16 + (l&15)]
// gate frags f = (g*16 + nf)*8 + kb   g:0=Z,1=H   nf<16 kb<8   -> [0,256)
// out  frags f = 256 + nf*8 + kb      nf<4                     -> [256,288)
__global__ __launch_bounds__(256) void prep_frags(
    const float* __restrict__ wz, const float* __restrict__ wh,
    const float* __restrict__ wlin, unsigned short* __restrict__ ws)
{
    int t = blockIdx.x * 256 + threadIdx.x;
    int frag = t >> 6, lane = t & 63;
    if (frag >= 288) return;
    int g16 = lane & 15, kg = lane >> 4;
    unsigned short vals[8];
    if (frag < 256) {
        int kb = frag & 7, nf = (frag >> 3) & 15, g = frag >> 7;
        const float* wsrc = g ? wh : wz;
        int n = nf * 16 + g16;
        #pragma unroll
        for (int j = 0; j < 8; ++j) {
            int k = kb * 32 + kg * 8 + j;
            float v = wsrc[k * 256 + n] + wsrc[131072 + k * 256 + n];  // tap0 + tap1
            vals[j] = f2bf(v);
        }
    } else {
        int f = frag - 256;
        int kb = f & 7, nf = f >> 3;
        int n = nf * 16 + g16;                       // output column o
        #pragma unroll
        for (int j = 0; j < 8; ++j) {
            int k = kb * 32 + kg * 8 + j;
            vals[j] = f2bf(wlin[n * 256 + k]);       // B[k][o] = w_lin[o][k]
        }
    }
    unsigned short* dst = ws + (size_t)frag * 512 + lane * 8;
    #pragma unroll
    for (int j = 0; j < 8; ++j) dst[j] = vals[j];
}

__device__ inline bf16x8 ldfrag(const unsigned short* wf, int frag, int lane) {
    return *reinterpret_cast<const bf16x8*>(wf + (size_t)frag * 512 + lane * 8);
}

// one gate iteration: A ds_reads -> vmcnt(WZ) -> Z weights -> lgkm0 -> stage Z(kb+1)
// -> 8 Z-MFMAs -> vmcnt(WH) -> H weights -> lgkm0 -> stage H(kb+1) -> 8 H-MFMAs.
// WZ/WH are literal strings; "63" = architectural no-op.
#define GATE_ITER(KB, WZ, WH, SN)                                                   \
    do {                                                                            \
        bf16x8 ah[4];                                                               \
        int koff = (KB) * 32 + lk * 8;                                              \
        _Pragma("unroll")                                                           \
        for (int m = 0; m < 4; ++m) {                                               \
            int row = m * 16 + l16;                                                 \
            int byte = ((row * CIN + koff) * 2) ^ ((row & 7) << 4);                 \
            ah[m] = *reinterpret_cast<const bf16x8*>(AhiB + byte);                  \
        }                                                                           \
        asm volatile("s_waitcnt vmcnt(" WZ ")" ::: "memory");                       \
        bf16x8 zb0 = *reinterpret_cast<const bf16x8*>(wbuf + lane * 16);            \
        bf16x8 zb1 = *reinterpret_cast<const bf16x8*>(wbuf + 1024 + lane * 16);     \
        asm volatile("s_waitcnt lgkmcnt(0)" ::: "memory");                          \
        if (SN) {                                                                   \
            gload16(wf + (size_t)((nf0)     * 8 + (KB) + 1) * 512 + lane * 8, wbuf);\
            gload16(wf + (size_t)((nf0 + 1) * 8 + (KB) + 1) * 512 + lane * 8, wbuf + 1024);\
        }                                                                           \
        _Pragma("unroll")                                                           \
        for (int m = 0; m < 4; ++m) {                                               \
            accZ[0][m] = mfma16(ah[m], zb0, accZ[0][m]);                            \
            accZ[1][m] = mfma16(ah[m], zb1, accZ[1][m]);                            \
        }                                                                           \
        asm volatile("s_waitcnt vmcnt(" WH ")" ::: "memory");                       \
        bf16x8 hb0 = *reinterpret_cast<const bf16x8*>(wbuf + 2048 + lane * 16);     \
        bf16x8 hb1 = *reinterpret_cast<const bf16x8*>(wbuf + 3072 + lane * 16);     \
        asm volatile("s_waitcnt lgkmcnt(0)" ::: "memory");                          \
        if (SN) {                                                                   \
            gload16(wf + (size_t)((16 + nf0)     * 8 + (KB) + 1) * 512 + lane * 8, wbuf + 2048);\
            gload16(wf + (size_t)((16 + nf0 + 1) * 8 + (KB) + 1) * 512 + lane * 8, wbuf + 3072);\
        }                                                                           \
        _Pragma("unroll")                                                           \
        for (int m = 0; m < 4; ++m) {                                               \
            accH[0][m] = mfma16(ah[m], hb0, accH[0][m]);                            \
            accH[1][m] = mfma16(ah[m], hb1, accH[1][m]);                            \
        }                                                                           \
    } while (0)

// ---------------- fused MFMA kernel: BM=64, k-split staging, async weight pipeline ----------------
__global__ __launch_bounds__(512)
__attribute__((amdgpu_waves_per_eu(4, 4)))
void dcrnn_async(
    const float* __restrict__ x, const float* __restrict__ mask,
    const unsigned short* __restrict__ wf,
    const float* __restrict__ bz, const float* __restrict__ bh,
    const float* __restrict__ blin, float* __restrict__ out)
{
    __shared__ char smem[65536];       // [0,32K): x_hi (64x256 bf16, swz); [32K,64K): 8 x 4KB dbufs
                                       // after gate loop: h (u32, 64 rows x 1KB) overlays all 64K
    char* AhiB = smem;
    const int tid = threadIdx.x, lane = tid & 63, wv = tid >> 6;   // wv in [0,8)
    const int l16 = lane & 15, lk = lane >> 4;
    const int row0 = blockIdx.x * BM;
    const int nf0 = wv * 2;            // this wave's 2 nf slices (cols wv*32..+32)
    char* wbuf = smem + 32768 + wv * 4096;   // private dbuf: Z frags +0,+1024; H +2048,+3072

    // ---- issue kb=0 weight stages first (in flight under half-1 x staging) ----
    gload16(wf + (size_t)((nf0)          * 8) * 512 + lane * 8, wbuf);
    gload16(wf + (size_t)((nf0 + 1)      * 8) * 512 + lane * 8, wbuf + 1024);
    gload16(wf + (size_t)((16 + nf0)     * 8) * 512 + lane * 8, wbuf + 2048);
    gload16(wf + (size_t)((16 + nf0 + 1) * 8) * 512 + lane * 8, wbuf + 3072);

    // ---- bias constants ----
    float bzv[2], bhv[2];
    #pragma unroll
    for (int nfi = 0; nfi < 2; ++nfi) {
        int col = wv * 32 + nfi * 16 + l16;
        bzv[nfi] = bz[col]; bhv[nfi] = bh[col];
    }
    const int ocol = (wv & 3) * 16 + l16;
    const float bo = blin[ocol];
    const int mo = wv >> 2;            // out-GEMM row half: rows [mo*32, mo*32+32)

    // ---- stage HALF-1 (k < 128): all 64 rows x 32 float4 cols ----
    const int r_st  = (tid >> 5);      // row within 16-row group
    const int c4_lo = tid & 31;        // float4 col in [0,32)
    #pragma unroll
    for (int it = 0; it < 4; ++it) {
        int r = it * 16 + r_st;
        int row = row0 + r;
        float4 xv = make_float4(0.f, 0.f, 0.f, 0.f), mv = xv;
        if (row < N_ROWS) {
            xv = reinterpret_cast<const float4*>(x    + (size_t)row * CIN)[c4_lo];
            mv = reinterpret_cast<const float4*>(mask + (size_t)row * CIN)[c4_lo];
        }
        unsigned short h0 = f2bf(xv.x * mv.x), h1 = f2bf(xv.y * mv.y);
        unsigned short h2 = f2bf(xv.z * mv.z), h3 = f2bf(xv.w * mv.w);
        int byte = ((r * CIN + c4_lo * 4) * 2) ^ ((r & 7) << 4);     // T2 swizzle (proven)
        *reinterpret_cast<ushort4*>(AhiB + byte) = make_ushort4(h0, h1, h2, h3);
    }
    __syncthreads();   // half-1 visible; barrier drains vmcnt -> kb=0 weights arrived

    // ---- issue half-2 chunk A loads (its 0,1 -> rows 0..31, k>=128), pin early ----
    const int c4_hi = 32 + (tid & 31); // float4 col in [32,64)
    float4 px[2], pm[2];
    #pragma unroll
    for (int j = 0; j < 2; ++j) {
        int r = j * 16 + r_st;
        int row = row0 + r;
        px[j] = make_float4(0.f, 0.f, 0.f, 0.f); pm[j] = px[j];
        if (row < N_ROWS) {
            px[j] = reinterpret_cast<const float4*>(x    + (size_t)row * CIN)[c4_hi];
            pm[j] = reinterpret_cast<const float4*>(mask + (size_t)row * CIN)[c4_hi];
        }
    }
    __builtin_amdgcn_sched_barrier(0);

    // ---- gate GEMMs ----
    f32x4 accZ[2][4], accH[2][4];      // [nfi][m]
    #pragma unroll
    for (int nfi = 0; nfi < 2; ++nfi)
        #pragma unroll
        for (int m = 0; m < 4; ++m) {
            accZ[nfi][m] = (f32x4){0.f, 0.f, 0.f, 0.f};
            accH[nfi][m] = (f32x4){0.f, 0.f, 0.f, 0.f};
        }

    GATE_ITER(0, "63", "63", 1);       // kb=0 arrived via barrier; stage kb=1
    GATE_ITER(1, "2", "2", 1);         // x chunk-A loads are oldest; over-drained here (old, free)

    // convert chunk A (compiler inserts precise wait for px/pm); write k>=128 rows 0..31
    #pragma unroll
    for (int j = 0; j < 2; ++j) {
        int r = j * 16 + r_st;
        unsigned short h0 = f2bf(px[j].x * pm[j].x), h1 = f2bf(px[j].y * pm[j].y);
        unsigned short h2 = f2bf(px[j].z * pm[j].z), h3 = f2bf(px[j].w * pm[j].w);
        int byte = ((r * CIN + c4_hi * 4) * 2) ^ ((r & 7) << 4);
        *reinterpret_cast<ushort4*>(AhiB + byte) = make_ushort4(h0, h1, h2, h3);
    }
    // issue chunk B loads (its 2,3 -> rows 32..63, k>=128)
    #pragma unroll
    for (int j = 0; j < 2; ++j) {
        int r = (2 + j) * 16 + r_st;
        int row = row0 + r;
        px[j] = make_float4(0.f, 0.f, 0.f, 0.f); pm[j] = px[j];
        if (row < N_ROWS) {
            px[j] = reinterpret_cast<const float4*>(x    + (size_t)row * CIN)[c4_hi];
            pm[j] = reinterpret_cast<const float4*>(mask + (size_t)row * CIN)[c4_hi];
        }
    }
    __builtin_amdgcn_sched_barrier(0);

    GATE_ITER(2, "6", "6", 1);         // skip the 4 in-flight x loads (hand-counted)

    // convert chunk B (compiler inserts precise wait; stage(3) stays in flight)
    #pragma unroll
    for (int j = 0; j < 2; ++j) {
        int r = (2 + j) * 16 + r_st;
        unsigned short h0 = f2bf(px[j].x * pm[j].x), h1 = f2bf(px[j].y * pm[j].y);
        unsigned short h2 = f2bf(px[j].z * pm[j].z), h3 = f2bf(px[j].w * pm[j].w);
        int byte = ((r * CIN + c4_hi * 4) * 2) ^ ((r & 7) << 4);
        *reinterpret_cast<ushort4*>(AhiB + byte) = make_ushort4(h0, h1, h2, h3);
    }

    GATE_ITER(3, "2", "2", 1);
    __syncthreads();                   // half-2 visible to ALL waves; drains stage(4) (arrived)
    GATE_ITER(4, "63", "63", 1);       // nothing outstanding; stage kb=5
    GATE_ITER(5, "2", "2", 1);
    GATE_ITER(6, "2", "2", 1);
    GATE_ITER(7, "2", "0", 0);         // last: drain H(7) fully, no trailing stage

    // depth-2 out-weight prefetch: first two frags land during the h phase
    bf16x8 cb0 = ldfrag(wf, 256 + (wv & 3) * 8 + 0, lane);
    bf16x8 cb1 = ldfrag(wf, 256 + (wv & 3) * 8 + 1, lane);
    __syncthreads();   // all waves done reading x/dbufs before h overwrites smem

    // ---- nonlinearities + GRU blend; h -> LDS as (bf16 bits << 16) u32 (word stores) ----
    #pragma unroll
    for (int nfi = 0; nfi < 2; ++nfi) {
        int col = wv * 32 + nfi * 16 + l16;
        #pragma unroll
        for (int m = 0; m < 4; ++m) {
            #pragma unroll
            for (int i = 0; i < 4; ++i) {
                float z  = 1.f / (1.f + __expf(-(accZ[nfi][m][i] + bzv[nfi])));
                float tt = __expf(2.f * (accH[nfi][m][i] + bhv[nfi]));
                float th = (tt - 1.f) / (tt + 1.f);
                float H  = (1.f - z) * th;
                float h  = (H > 0.f) ? H : (__expf(H) - 1.f);   // elu(alpha=1)
                int row = m * 16 + lk * 4 + i;                  // C/D: row=(lane>>4)*4+reg
                unsigned pk = ((unsigned)f2bf(h)) << 16;
                int byte = (row * 1024 + col * 4) ^ ((row & 7) << 4);  // u32, row stride 1 KB
                *reinterpret_cast<unsigned*>(smem + byte) = pk;
            }
        }
    }
    __syncthreads();   // h visible to all waves

    // ---- out GEMM: wave wv -> rows [mo*32, +32) (2 m-frags), out-cols [(wv&3)*16,+16) ----
    f32x4 accO[2];
    accO[0] = (f32x4){0.f, 0.f, 0.f, 0.f};
    accO[1] = (f32x4){0.f, 0.f, 0.f, 0.f};
    #pragma unroll
    for (int kb = 0; kb < 8; ++kb) {
        bf16x8 cur = (kb & 1) ? cb1 : cb0;
        if (kb + 2 < 8) {                              // depth-2 ping-pong refill
            bf16x8 nf_ = ldfrag(wf, 256 + (wv & 3) * 8 + kb + 2, lane);
            if (kb & 1) cb1 = nf_; else cb0 = nf_;
        }
        #pragma unroll
        for (int m = 0; m < 2; ++m) {
            int row = mo * 32 + m * 16 + l16;
            int e0  = kb * 32 + lk * 8;
            int b0  = (row * 1024 + e0 * 4)      ^ ((row & 7) << 4);
            int b1  = (row * 1024 + e0 * 4 + 16) ^ ((row & 7) << 4);
            uint4 p0 = *reinterpret_cast<const uint4*>(smem + b0);
            uint4 p1 = *reinterpret_cast<const uint4*>(smem + b1);
            bf16x8 ha;
            ha[0] = (short)(p0.x >> 16); ha[1] = (short)(p0.y >> 16);
            ha[2] = (short)(p0.z >> 16); ha[3] = (short)(p0.w >> 16);
            ha[4] = (short)(p1.x >> 16); ha[5] = (short)(p1.y >> 16);
            ha[6] = (short)(p1.z >> 16); ha[7] = (short)(p1.w >> 16);
            accO[m] = mfma16(ha, cur, accO[m]);
        }
    }
    #pragma unroll
    for (int m = 0; m < 2; ++m)
        #pragma unroll
        for (int i = 0; i < 4; ++i) {
            int row = row0 + mo * 32 + m * 16 + lk * 4 + i;
            if (row < N_ROWS) out[(size_t)row * COUT + ocol] = accO[m][i] + bo;
        }
}

// ---------------- fallback: round-2 f32 kernel (proven; used only if ws too small) ----------------
__global__ __launch_bounds__(256) void fallback_f32(
    const float* __restrict__ x, const float* __restrict__ mask,
    const float* __restrict__ wzr, const float* __restrict__ whr,
    const float* __restrict__ bz, const float* __restrict__ bh,
    const float* __restrict__ wlinr, const float* __restrict__ blin,
    float* __restrict__ out)
{
    __shared__ float xm[32][CIN];
    const int tid = threadIdx.x;
    const int row0 = blockIdx.x * 32;
    #pragma unroll
    for (int it = 0; it < 8; ++it) {
        int idx = it * 256 + tid;
        int r = idx >> 6, c4 = idx & 63, row = row0 + r;
        float4 v = make_float4(0.f, 0.f, 0.f, 0.f);
        if (row < N_ROWS) {
            float4 a = reinterpret_cast<const float4*>(x    + (size_t)row * CIN)[c4];
            float4 m = reinterpret_cast<const float4*>(mask + (size_t)row * CIN)[c4];
            v = make_float4(a.x * m.x, a.y * m.y, a.z * m.z, a.w * m.w);
        }
        reinterpret_cast<float4*>(&xm[r][0])[c4] = v;
    }
    __syncthreads();
    const int j0 = (tid & 63) * 4, r0 = (tid >> 6) * 8;
    float accz[4][8], acch[4][8];
    #pragma unroll
    for (int c = 0; c < 4; ++c)
        #pragma unroll
        for (int r = 0; r < 8; ++r) { accz[c][r] = 0.f; acch[c][r] = 0.f; }
    for (int k = 0; k < CIN; k += 4) {
        float4 wz4[4], wh4[4];
        #pragma unroll
        for (int kk = 0; kk < 4; ++kk) {
            float4 a0 = *reinterpret_cast<const float4*>(&wzr[(k + kk) * 256 + j0]);
            float4 a1 = *reinterpret_cast<const float4*>(&wzr[131072 + (k + kk) * 256 + j0]);
            wz4[kk] = make_float4(a0.x + a1.x, a0.y + a1.y, a0.z + a1.z, a0.w + a1.w);
            float4 b0 = *reinterpret_cast<const float4*>(&whr[(k + kk) * 256 + j0]);
            float4 b1 = *reinterpret_cast<const float4*>(&whr[131072 + (k + kk) * 256 + j0]);
            wh4[kk] = make_float4(b0.x + b1.x, b0.y + b1.y, b0.z + b1.z, b0.w + b1.w);
        }
        #pragma unroll
        for (int r = 0; r < 8; ++r) {
            float4 xv = *reinterpret_cast<const float4*>(&xm[r0 + r][k]);
            float xk[4] = {xv.x, xv.y, xv.z, xv.w};
            float wzc[4][4] = {{wz4[0].x,wz4[0].y,wz4[0].z,wz4[0].w},{wz4[1].x,wz4[1].y,wz4[1].z,wz4[1].w},
                               {wz4[2].x,wz4[2].y,wz4[2].z,wz4[2].w},{wz4[3].x,wz4[3].y,wz4[3].z,wz4[3].w}};
            float whc[4][4] = {{wh4[0].x,wh4[0].y,wh4[0].z,wh4[0].w},{wh4[1].x,wh4[1].y,wh4[1].z,wh4[1].w},
                               {wh4[2].x,wh4[2].y,wh4[2].z,wh4[2].w},{wh4[3].x,wh4[3].y,wh4[3].z,wh4[3].w}};
            #pragma unroll
            for (int kk = 0; kk < 4; ++kk)
                #pragma unroll
                for (int c = 0; c < 4; ++c) {
                    accz[c][r] = fmaf(xk[kk], wzc[kk][c], accz[c][r]);
                    acch[c][r] = fmaf(xk[kk], whc[kk][c], acch[c][r]);
                }
        }
    }
    float bzj[4], bhj[4];
    #pragma unroll
    for (int c = 0; c < 4; ++c) { bzj[c] = bz[j0 + c]; bhj[c] = bh[j0 + c]; }
    __syncthreads();
    #pragma unroll
    for (int r = 0; r < 8; ++r) {
        float hc[4];
        #pragma unroll
        for (int c = 0; c < 4; ++c) {
            float z  = 1.f / (1.f + expf(-(accz[c][r] + bzj[c])));
            float ht = tanhf(acch[c][r] + bhj[c]);
            float H  = (1.f - z) * ht;
            hc[c] = (H > 0.f) ? H : expm1f(H);
        }
        *reinterpret_cast<float4*>(&xm[r0 + r][j0]) = make_float4(hc[0], hc[1], hc[2], hc[3]);
    }
    __syncthreads();
    const int o = tid & 63;
    float acc[8];
    #pragma unroll
    for (int r = 0; r < 8; ++r) acc[r] = 0.f;
    for (int k = 0; k < CIN; k += 4) {
        float4 wv4 = *reinterpret_cast<const float4*>(&wlinr[o * 256 + k]);
        #pragma unroll
        for (int r = 0; r < 8; ++r) {
            float4 hv = *reinterpret_cast<const float4*>(&xm[r0 + r][k]);
            acc[r] = fmaf(hv.x, wv4.x, acc[r]);
            acc[r] = fmaf(hv.y, wv4.y, acc[r]);
            acc[r] = fmaf(hv.z, wv4.z, acc[r]);
            acc[r] = fmaf(hv.w, wv4.w, acc[r]);
        }
    }
    float bo = blin[o];
    #pragma unroll
    for (int r = 0; r < 8; ++r) {
        int row = row0 + r0 + r;
        if (row < N_ROWS) out[(size_t)row * COUT + o] = acc[r] + bo;
    }
}

extern "C" void kernel_launch(void* const* d_in, const int* in_sizes, int n_in,
                              void* d_out, int out_size, void* d_ws, size_t ws_size,
                              hipStream_t stream)
{
    const float* x    = (const float*)d_in[0];
    // d_in[1] edge_index, d_in[2] edge_weight: unused (K=1 identity term only)
    const float* mask = (const float*)d_in[3];
    const float* wz   = (const float*)d_in[4];
    const float* bz   = (const float*)d_in[5];
    // d_in[6] w_r, d_in[7] b_r: dead (H=0 -> reset gate unused)
    const float* wh   = (const float*)d_in[8];
    const float* bh   = (const float*)d_in[9];
    const float* wlin = (const float*)d_in[10];
    const float* blin = (const float*)d_in[11];
    float* outf = (float*)d_out;

    const size_t ws_need = 288 * 1024;   // 288 frags x 1 KB
    if (ws_size >= ws_need) {
        unsigned short* wsf = (unsigned short*)d_ws;
        prep_frags<<<72, 256, 0, stream>>>(wz, wh, wlin, wsf);
        dcrnn_async<<<(N_ROWS + BM - 1) / BM, 512, 0, stream>>>(
            x, mask, wsf, bz, bh, blin, outf);
    } else {
        fallback_f32<<<(N_ROWS + 31) / 32, 256, 0, stream>>>(
            x, mask, wz, wh, bz, bh, wlin, blin, outf);
    }
}

// Round 17
// 56.362 us; speedup vs baseline: 1.3660x; 1.3660x over previous
//
#include <hip/hip_runtime.h>
#include <hip/hip_bf16.h>

// DCRNN single-step, algebraically reduced (proven rounds 2-16):
//   xm = x * mask
//   Z  = sigmoid(xm @ WzE + bz),  WzE = w_z[0,0][:256] + w_z[1,0][:256]
//   Ht = tanh   (xm @ WhE + bh)
//   h  = elu((1 - Z) * Ht)         // H=0 -> Z*H drops; R/w_r/b_r dead; edges dead
//   out = h @ w_lin.T + b_lin      // f32 output
//
// Precision: single-bf16 MFMA both sides (x-hi * W-hi), absmax 0.015625.
// Round-17: REVERT to the R13 kernel exactly (best measured: 56.2 us).
// R14 (merged vmcnt(0) drain), R15 (zero-copy out-GEMM), R16 (k-split staging)
// all failed to beat it; R16 regressed (FETCH 52->81 MB, L3 locality broken).
// R13 = BM=64, 512 threads/8 waves, per-wave private LDS weight double-buffers
// streamed via global_load_lds with counted wave-local vmcnt(2) (allocator-proof),
// h transported as (bf16<<16) u32 words, out-weights depth-1 register prefetch.

typedef __attribute__((ext_vector_type(8))) short bf16x8;   // 8 bf16 = 4 VGPR
typedef __attribute__((ext_vector_type(4))) float f32x4;

constexpr int N_ROWS = 50000;
constexpr int CIN  = 256;
constexpr int COUT = 64;
constexpr int BM   = 64;

__device__ inline unsigned short f2bf(float f) {          // RNE f32 -> bf16 bits
    union { float f; unsigned u; } v; v.f = f;
    unsigned r = v.u + 0x7fffu + ((v.u >> 16) & 1u);
    return (unsigned short)(r >> 16);
}
__device__ inline f32x4 mfma16(bf16x8 a, bf16x8 b, f32x4 c) {
    return __builtin_amdgcn_mfma_f32_16x16x32_bf16(a, b, c, 0, 0, 0);
}
__device__ __forceinline__ void gload16(const void* g, void* l) {
    // one fragment: 64 lanes x 16 B -> LDS at base + lane*16 (async, vmcnt-counted)
    __builtin_amdgcn_global_load_lds(
        (const __attribute__((address_space(1))) char*)g,
        (__attribute__((address_space(3))) char*)l, 16, 0, 0);
}

// ---------------- weight prep: B-fragment-ordered bf16 (hi only; proven R7-R16) ----------------
// Fragment f holds, for lane l, 8 bf16: B[k = kb*32 + (l>>4)*8 + j][n = nf*16 + (l&15)]
// gate frags f = (g*16 + nf)*8 + kb   g:0=Z,1=H   nf<16 kb<8   -> [0,256)
// out  frags f = 256 + nf*8 + kb      nf<4                     -> [256,288)
__global__ __launch_bounds__(256) void prep_frags(
    const float* __restrict__ wz, const float* __restrict__ wh,
    const float* __restrict__ wlin, unsigned short* __restrict__ ws)
{
    int t = blockIdx.x * 256 + threadIdx.x;
    int frag = t >> 6, lane = t & 63;
    if (frag >= 288) return;
    int g16 = lane & 15, kg = lane >> 4;
    unsigned short vals[8];
    if (frag < 256) {
        int kb = frag & 7, nf = (frag >> 3) & 15, g = frag >> 7;
        const float* wsrc = g ? wh : wz;
        int n = nf * 16 + g16;
        #pragma unroll
        for (int j = 0; j < 8; ++j) {
            int k = kb * 32 + kg * 8 + j;
            float v = wsrc[k * 256 + n] + wsrc[131072 + k * 256 + n];  // tap0 + tap1
            vals[j] = f2bf(v);
        }
    } else {
        int f = frag - 256;
        int kb = f & 7, nf = f >> 3;
        int n = nf * 16 + g16;                       // output column o
        #pragma unroll
        for (int j = 0; j < 8; ++j) {
            int k = kb * 32 + kg * 8 + j;
            vals[j] = f2bf(wlin[n * 256 + k]);       // B[k][o] = w_lin[o][k]
        }
    }
    unsigned short* dst = ws + (size_t)frag * 512 + lane * 8;
    #pragma unroll
    for (int j = 0; j < 8; ++j) dst[j] = vals[j];
}

__device__ inline bf16x8 ldfrag(const unsigned short* wf, int frag, int lane) {
    return *reinterpret_cast<const bf16x8*>(wf + (size_t)frag * 512 + lane * 8);
}

// ---------------- fused MFMA kernel: BM=64, async weight pipeline (R13) ----------------
__global__ __launch_bounds__(512)
__attribute__((amdgpu_waves_per_eu(4, 4)))
void dcrnn_async(
    const float* __restrict__ x, const float* __restrict__ mask,
    const unsigned short* __restrict__ wf,
    const float* __restrict__ bz, const float* __restrict__ bh,
    const float* __restrict__ blin, float* __restrict__ out)
{
    __shared__ char smem[65536];       // [0,32K): x_hi (64x256 bf16, swz); [32K,64K): 8 x 4KB dbufs
                                       // after gate barrier: h (u32, 64 rows x 1KB) overlays all 64K
    char* AhiB = smem;
    const int tid = threadIdx.x, lane = tid & 63, wv = tid >> 6;   // wv in [0,8)
    const int l16 = lane & 15, lk = lane >> 4;
    const int row0 = blockIdx.x * BM;
    const int nf0 = wv * 2;            // this wave's 2 nf slices (cols wv*32..+32)
    char* wbuf = smem + 32768 + wv * 4096;   // private dbuf: Z->half0 (+0), H->half1 (+2048)

    auto stage_gate = [&](int kb, int g) {   // 2 frags (nf0, nf0+1) of gate g at kb
        char* dst = wbuf + g * 2048;
        gload16(wf + (size_t)((g * 16 + nf0)     * 8 + kb) * 512 + lane * 8, dst);
        gload16(wf + (size_t)((g * 16 + nf0 + 1) * 8 + kb) * 512 + lane * 8, dst + 1024);
    };

    // ---- issue kb=0 weight stages first (in flight under x staging) ----
    stage_gate(0, 0);
    stage_gate(0, 1);

    // ---- bias constants ----
    float bzv[2], bhv[2];
    #pragma unroll
    for (int nfi = 0; nfi < 2; ++nfi) {
        int col = wv * 32 + nfi * 16 + l16;
        bzv[nfi] = bz[col]; bhv[nfi] = bh[col];
    }
    const int ocol = (wv & 3) * 16 + l16;
    const float bo = blin[ocol];
    const int mo = wv >> 2;            // out-GEMM row half: rows [mo*32, mo*32+32)

    // ---- stage xm = x*mask -> bf16(hi) in LDS (f32x4 loads, swizzled 8B writes) ----
    #pragma unroll
    for (int it = 0; it < 8; ++it) {
        int s = it * 512 + tid, r = s >> 6, c4 = s & 63;   // r in [0,64)
        int row = row0 + r;
        float4 xv = make_float4(0.f, 0.f, 0.f, 0.f), mv = xv;
        if (row < N_ROWS) {
            xv = reinterpret_cast<const float4*>(x    + (size_t)row * CIN)[c4];
            mv = reinterpret_cast<const float4*>(mask + (size_t)row * CIN)[c4];
        }
        unsigned short h0 = f2bf(xv.x * mv.x), h1 = f2bf(xv.y * mv.y);
        unsigned short h2 = f2bf(xv.z * mv.z), h3 = f2bf(xv.w * mv.w);
        int byte = ((r * CIN + c4 * 4) * 2) ^ ((r & 7) << 4);     // T2 swizzle (proven)
        *reinterpret_cast<ushort4*>(AhiB + byte) = make_ushort4(h0, h1, h2, h3);
    }
    __syncthreads();   // x tile visible; barrier drains vmcnt -> kb=0 stages arrived

    // ---- gate GEMMs: 4 m-frags x 2 nf, weights via async LDS dbuf ----
    f32x4 accZ[2][4], accH[2][4];      // [nfi][m]
    #pragma unroll
    for (int nfi = 0; nfi < 2; ++nfi)
        #pragma unroll
        for (int m = 0; m < 4; ++m) {
            accZ[nfi][m] = (f32x4){0.f, 0.f, 0.f, 0.f};
            accH[nfi][m] = (f32x4){0.f, 0.f, 0.f, 0.f};
        }

    for (int kb = 0; kb < 8; ++kb) {
        bf16x8 ah[4];
        int koff = kb * 32 + lk * 8;
        #pragma unroll
        for (int m = 0; m < 4; ++m) {
            int row = m * 16 + l16;
            int byte = ((row * CIN + koff) * 2) ^ ((row & 7) << 4);
            ah[m] = *reinterpret_cast<const bf16x8*>(AhiB + byte);
        }
        // --- Z unit (half0): steady-state outstanding = {Z(kb),H(kb)} = 4 loads ---
        if (kb >= 1) asm volatile("s_waitcnt vmcnt(2)" ::: "memory");   // Z(kb) arrived
        bf16x8 zb0 = *reinterpret_cast<const bf16x8*>(wbuf + lane * 16);
        bf16x8 zb1 = *reinterpret_cast<const bf16x8*>(wbuf + 1024 + lane * 16);
        asm volatile("s_waitcnt lgkmcnt(0)" ::: "memory");              // zb in VGPRs before overwrite
        if (kb < 7) stage_gate(kb + 1, 0);
        #pragma unroll
        for (int m = 0; m < 4; ++m) {
            accZ[0][m] = mfma16(ah[m], zb0, accZ[0][m]);
            accZ[1][m] = mfma16(ah[m], zb1, accZ[1][m]);
        }
        // --- H unit (half1) ---
        if (kb == 7)      asm volatile("s_waitcnt vmcnt(0)" ::: "memory");  // no trailing stage
        else if (kb >= 1) asm volatile("s_waitcnt vmcnt(2)" ::: "memory");  // H(kb) arrived
        bf16x8 hb0 = *reinterpret_cast<const bf16x8*>(wbuf + 2048 + lane * 16);
        bf16x8 hb1 = *reinterpret_cast<const bf16x8*>(wbuf + 3072 + lane * 16);
        asm volatile("s_waitcnt lgkmcnt(0)" ::: "memory");
        if (kb < 7) stage_gate(kb + 1, 1);
        #pragma unroll
        for (int m = 0; m < 4; ++m) {
            accH[0][m] = mfma16(ah[m], hb0, accH[0][m]);
            accH[1][m] = mfma16(ah[m], hb1, accH[1][m]);
        }
    }
    // issue first out-weight load (global->VGPR) before the barrier
    bf16x8 cb = ldfrag(wf, 256 + (wv & 3) * 8, lane);
    __syncthreads();   // all waves done reading x/dbufs before h overwrites smem

    // ---- nonlinearities + GRU blend; h -> LDS as (bf16 bits << 16) u32 (word stores) ----
    #pragma unroll
    for (int nfi = 0; nfi < 2; ++nfi) {
        int col = wv * 32 + nfi * 16 + l16;
        #pragma unroll
        for (int m = 0; m < 4; ++m) {
            #pragma unroll
            for (int i = 0; i < 4; ++i) {
                float z  = 1.f / (1.f + __expf(-(accZ[nfi][m][i] + bzv[nfi])));
                float tt = __expf(2.f * (accH[nfi][m][i] + bhv[nfi]));
                float th = (tt - 1.f) / (tt + 1.f);
                float H  = (1.f - z) * th;
                float h  = (H > 0.f) ? H : (__expf(H) - 1.f);   // elu(alpha=1)
                int row = m * 16 + lk * 4 + i;                  // C/D: row=(lane>>4)*4+reg
                unsigned pk = ((unsigned)f2bf(h)) << 16;
                int byte = (row * 1024 + col * 4) ^ ((row & 7) << 4);  // u32, row stride 1 KB
                *reinterpret_cast<unsigned*>(smem + byte) = pk;
            }
        }
    }
    __syncthreads();   // h visible to all waves

    // ---- out GEMM: wave wv -> rows [mo*32, +32) (2 m-frags), out-cols [(wv&3)*16,+16) ----
    f32x4 accO[2];
    accO[0] = (f32x4){0.f, 0.f, 0.f, 0.f};
    accO[1] = (f32x4){0.f, 0.f, 0.f, 0.f};
    for (int kb = 0; kb < 8; ++kb) {
        int nk = kb < 7 ? kb + 1 : 7;
        bf16x8 nb = ldfrag(wf, 256 + (wv & 3) * 8 + nk, lane);    // depth-1 prefetch
        #pragma unroll
        for (int m = 0; m < 2; ++m) {
            int row = mo * 32 + m * 16 + l16;
            int e0  = kb * 32 + lk * 8;
            int b0  = (row * 1024 + e0 * 4)      ^ ((row & 7) << 4);
            int b1  = (row * 1024 + e0 * 4 + 16) ^ ((row & 7) << 4);
            uint4 p0 = *reinterpret_cast<const uint4*>(smem + b0);
            uint4 p1 = *reinterpret_cast<const uint4*>(smem + b1);
            bf16x8 ha;
            ha[0] = (short)(p0.x >> 16); ha[1] = (short)(p0.y >> 16);
            ha[2] = (short)(p0.z >> 16); ha[3] = (short)(p0.w >> 16);
            ha[4] = (short)(p1.x >> 16); ha[5] = (short)(p1.y >> 16);
            ha[6] = (short)(p1.z >> 16); ha[7] = (short)(p1.w >> 16);
            accO[m] = mfma16(ha, cb, accO[m]);
        }
        cb = nb;
    }
    #pragma unroll
    for (int m = 0; m < 2; ++m)
        #pragma unroll
        for (int i = 0; i < 4; ++i) {
            int row = row0 + mo * 32 + m * 16 + lk * 4 + i;
            if (row < N_ROWS) out[(size_t)row * COUT + ocol] = accO[m][i] + bo;
        }
}

// ---------------- fallback: round-2 f32 kernel (proven; used only if ws too small) ----------------
__global__ __launch_bounds__(256) void fallback_f32(
    const float* __restrict__ x, const float* __restrict__ mask,
    const float* __restrict__ wzr, const float* __restrict__ whr,
    const float* __restrict__ bz, const float* __restrict__ bh,
    const float* __restrict__ wlinr, const float* __restrict__ blin,
    float* __restrict__ out)
{
    __shared__ float xm[32][CIN];
    const int tid = threadIdx.x;
    const int row0 = blockIdx.x * 32;
    #pragma unroll
    for (int it = 0; it < 8; ++it) {
        int idx = it * 256 + tid;
        int r = idx >> 6, c4 = idx & 63, row = row0 + r;
        float4 v = make_float4(0.f, 0.f, 0.f, 0.f);
        if (row < N_ROWS) {
            float4 a = reinterpret_cast<const float4*>(x    + (size_t)row * CIN)[c4];
            float4 m = reinterpret_cast<const float4*>(mask + (size_t)row * CIN)[c4];
            v = make_float4(a.x * m.x, a.y * m.y, a.z * m.z, a.w * m.w);
        }
        reinterpret_cast<float4*>(&xm[r][0])[c4] = v;
    }
    __syncthreads();
    const int j0 = (tid & 63) * 4, r0 = (tid >> 6) * 8;
    float accz[4][8], acch[4][8];
    #pragma unroll
    for (int c = 0; c < 4; ++c)
        #pragma unroll
        for (int r = 0; r < 8; ++r) { accz[c][r] = 0.f; acch[c][r] = 0.f; }
    for (int k = 0; k < CIN; k += 4) {
        float4 wz4[4], wh4[4];
        #pragma unroll
        for (int kk = 0; kk < 4; ++kk) {
            float4 a0 = *reinterpret_cast<const float4*>(&wzr[(k + kk) * 256 + j0]);
            float4 a1 = *reinterpret_cast<const float4*>(&wzr[131072 + (k + kk) * 256 + j0]);
            wz4[kk] = make_float4(a0.x + a1.x, a0.y + a1.y, a0.z + a1.z, a0.w + a1.w);
            float4 b0 = *reinterpret_cast<const float4*>(&whr[(k + kk) * 256 + j0]);
            float4 b1 = *reinterpret_cast<const float4*>(&whr[131072 + (k + kk) * 256 + j0]);
            wh4[kk] = make_float4(b0.x + b1.x, b0.y + b1.y, b0.z + b1.z, b0.w + b1.w);
        }
        #pragma unroll
        for (int r = 0; r < 8; ++r) {
            float4 xv = *reinterpret_cast<const float4*>(&xm[r0 + r][k]);
            float xk[4] = {xv.x, xv.y, xv.z, xv.w};
            float wzc[4][4] = {{wz4[0].x,wz4[0].y,wz4[0].z,wz4[0].w},{wz4[1].x,wz4[1].y,wz4[1].z,wz4[1].w},
                               {wz4[2].x,wz4[2].y,wz4[2].z,wz4[2].w},{wz4[3].x,wz4[3].y,wz4[3].z,wz4[3].w}};
            float whc[4][4] = {{wh4[0].x,wh4[0].y,wh4[0].z,wh4[0].w},{wh4[1].x,wh4[1].y,wh4[1].z,wh4[1].w},
                               {wh4[2].x,wh4[2].y,wh4[2].z,wh4[2].w},{wh4[3].x,wh4[3].y,wh4[3].z,wh4[3].w}};
            #pragma unroll
            for (int kk = 0; kk < 4; ++kk)
                #pragma unroll
                for (int c = 0; c < 4; ++c) {
                    accz[c][r] = fmaf(xk[kk], wzc[kk][c], accz[c][r]);
                    acch[c][r] = fmaf(xk[kk], whc[kk][c], acch[c][r]);
                }
        }
    }
    float bzj[4], bhj[4];
    #pragma unroll
    for (int c = 0; c < 4; ++c) { bzj[c] = bz[j0 + c]; bhj[c] = bh[j0 + c]; }
    __syncthreads();
    #pragma unroll
    for (int r = 0; r < 8; ++r) {
        float hc[4];
        #pragma unroll
        for (int c = 0; c < 4; ++c) {
            float z  = 1.f / (1.f + expf(-(accz[c][r] + bzj[c])));
            float ht = tanhf(acch[c][r] + bhj[c]);
            float H  = (1.f - z) * ht;
            hc[c] = (H > 0.f) ? H : expm1f(H);
        }
        *reinterpret_cast<float4*>(&xm[r0 + r][j0]) = make_float4(hc[0], hc[1], hc[2], hc[3]);
    }
    __syncthreads();
    const int o = tid & 63;
    float acc[8];
    #pragma unroll
    for (int r = 0; r < 8; ++r) acc[r] = 0.f;
    for (int k = 0; k < CIN; k += 4) {
        float4 wv4 = *reinterpret_cast<const float4*>(&wlinr[o * 256 + k]);
        #pragma unroll
        for (int r = 0; r < 8; ++r) {
            float4 hv = *reinterpret_cast<const float4*>(&xm[r0 + r][k]);
            acc[r] = fmaf(hv.x, wv4.x, acc[r]);
            acc[r] = fmaf(hv.y, wv4.y, acc[r]);
            acc[r] = fmaf(hv.z, wv4.z, acc[r]);
            acc[r] = fmaf(hv.w, wv4.w, acc[r]);
        }
    }
    float bo = blin[o];
    #pragma unroll
    for (int r = 0; r < 8; ++r) {
        int row = row0 + r0 + r;
        if (row < N_ROWS) out[(size_t)row * COUT + o] = acc[r] + bo;
    }
}

extern "C" void kernel_launch(void* const* d_in, const int* in_sizes, int n_in,
                              void* d_out, int out_size, void* d_ws, size_t ws_size,
                              hipStream_t stream)
{
    const float* x    = (const float*)d_in[0];
    // d_in[1] edge_index, d_in[2] edge_weight: unused (K=1 identity term only)
    const float* mask = (const float*)d_in[3];
    const float* wz   = (const float*)d_in[4];
    const float* bz   = (const float*)d_in[5];
    // d_in[6] w_r, d_in[7] b_r: dead (H=0 -> reset gate unused)
    const float* wh   = (const float*)d_in[8];
    const float* bh   = (const float*)d_in[9];
    const float* wlin = (const float*)d_in[10];
    const float* blin = (const float*)d_in[11];
    float* outf = (float*)d_out;

    const size_t ws_need = 288 * 1024;   // 288 frags x 1 KB
    if (ws_size >= ws_need) {
        unsigned short* wsf = (unsigned short*)d_ws;
        prep_frags<<<72, 256, 0, stream>>>(wz, wh, wlin, wsf);
        dcrnn_async<<<(N_ROWS + BM - 1) / BM, 512, 0, stream>>>(
            x, mask, wsf, bz, bh, blin, outf);
    } else {
        fallback_f32<<<(N_ROWS + 31) / 32, 256, 0, stream>>>(
            x, mask, wz, wh, bz, bh, wlin, blin, outf);
    }
}